// Round 1
// baseline (263.550 us; speedup 1.0000x reference)
//
#include <hip/hip_runtime.h>
#include <stdint.h>

#define N_NODES   50000
#define N_EDGES   400000
#define IN_FEATS  16
#define HIDDEN    32
#define K1        128      // EDGE_MLP_HID
#define NOUT      512      // IN_FEATS*HIDDEN
#define N_CLS     100000
#define TILE_E    64

typedef float  f32x4  __attribute__((ext_vector_type(4)));
typedef __bf16 bf16x8 __attribute__((ext_vector_type(8)));

__device__ __forceinline__ unsigned short f32_bf16(float f) {
    union { float f; uint32_t u; } c; c.f = f;
    uint32_t r = c.u + 0x7fffu + ((c.u >> 16) & 1u);
    return (unsigned short)(r >> 16);
}

// ---------------- prep: W2 [128,512] -> W2T bf16 [512,128]; W1 [16,128] -> W1T bf16 [128,32] (K padded) ----
__global__ void prep_weights(const float* __restrict__ w2, const float* __restrict__ w1,
                             unsigned short* __restrict__ w2t, unsigned short* __restrict__ w1t) {
    int tid = blockIdx.x * 256 + threadIdx.x;
    if (tid < NOUT * K1) {
        int n = tid >> 7, k = tid & 127;
        w2t[n * 128 + k] = f32_bf16(w2[k * 512 + n]);
    } else {
        int t = tid - NOUT * K1;            // [0, 4096)
        int n = t >> 5, k = t & 31;
        w1t[n * 32 + k] = (k < 16) ? f32_bf16(w1[k * 128 + n]) : (unsigned short)0;
    }
}

__global__ void zero_f32(float* __restrict__ p, int n) {
    int i = blockIdx.x * 256 + threadIdx.x;
    if (i < n) p[i] = 0.0f;
}

// ---------------- fused: edge MLP (MFMA) + per-edge matvec + scatter-add ----------------
__global__ __launch_bounds__(256) void fused_msg(
    const float* __restrict__ nf, const float* __restrict__ ef,
    const int* __restrict__ src, const int* __restrict__ dst,
    const unsigned short* __restrict__ w1t, const float* __restrict__ b1,
    const unsigned short* __restrict__ w2t, const float* __restrict__ b2,
    float* __restrict__ agg, float* __restrict__ deg)
{
    __shared__ __align__(16) unsigned short sW1T[128 * 32];   // [n=relu1 col][k] swizzled
    __shared__ __align__(16) unsigned short sAef[64 * 32];    // edge feats, K padded, swizzled
    __shared__ __align__(16) unsigned short sA[64 * 128];     // relu1 bf16, swizzled
    __shared__ __align__(16) unsigned short sB[128 * 128];    // W2T chunk [n][k], swizzled
    __shared__ __align__(16) float sX[64 * 16];               // gathered src node feats
    __shared__ float sB1[128];
    __shared__ float sB2[512];
    __shared__ int   sSrc[64], sDst[64];

    const int tid  = threadIdx.x;
    const int e0   = blockIdx.x * TILE_E;
    const int lane = tid & 63;
    const int w    = tid >> 6;      // wave 0..3
    const int l15  = lane & 15;
    const int lg   = lane >> 4;     // 0..3

    if (tid < 64)  { sSrc[tid] = src[e0 + tid]; sDst[tid] = dst[e0 + tid]; }
    if (tid < 128) sB1[tid] = b1[tid];
    for (int i = tid; i < 512; i += 256) sB2[i] = b2[i];

    // stage W1T (4096 bf16), swizzle k ^= (n&3)<<3
    #pragma unroll
    for (int p = 0; p < 2; ++p) {
        int idx = p * 2048 + tid * 8;
        int n = idx >> 5, k0 = idx & 31;
        uint4 v = *reinterpret_cast<const uint4*>(&w1t[idx]);
        *reinterpret_cast<uint4*>(&sW1T[n * 32 + (k0 ^ ((n & 3) << 3))]) = v;
    }
    // stage edge-feat tile as bf16 A [64][32] (k>=16 zero), swizzle k ^= (e&3)<<3
    {
        int idx = tid * 8;
        int e = idx >> 5, k0 = idx & 31;
        unsigned short tmp[8];
        if (k0 < 16) {
            float4 f0 = *reinterpret_cast<const float4*>(&ef[(e0 + e) * 16 + k0]);
            float4 f1 = *reinterpret_cast<const float4*>(&ef[(e0 + e) * 16 + k0 + 4]);
            tmp[0] = f32_bf16(f0.x); tmp[1] = f32_bf16(f0.y); tmp[2] = f32_bf16(f0.z); tmp[3] = f32_bf16(f0.w);
            tmp[4] = f32_bf16(f1.x); tmp[5] = f32_bf16(f1.y); tmp[6] = f32_bf16(f1.z); tmp[7] = f32_bf16(f1.w);
        } else {
            #pragma unroll
            for (int j = 0; j < 8; ++j) tmp[j] = 0;
        }
        *reinterpret_cast<uint4*>(&sAef[e * 32 + (k0 ^ ((e & 3) << 3))]) = *reinterpret_cast<const uint4*>(tmp);
    }
    __syncthreads();

    // gather src node features (64 edges x 16 floats)
    {
        int e = tid >> 2, q = tid & 3;
        float4 v = *reinterpret_cast<const float4*>(&nf[sSrc[e] * 16 + q * 4]);
        *reinterpret_cast<float4*>(&sX[e * 16 + q * 4]) = v;
    }
    if (tid < 64) atomicAdd(&deg[sDst[tid]], 1.0f);

    // layer 1 via MFMA: relu1[64][128] = relu(Aef[64][32] @ W1T + b1) -> sA bf16
    {
        int row = w * 16 + l15;
        bf16x8 a = *reinterpret_cast<const bf16x8*>(&sAef[row * 32 + ((lg * 8) ^ ((row & 3) << 3))]);
        #pragma unroll
        for (int f = 0; f < 8; ++f) {
            int n = f * 16 + l15;
            bf16x8 b = *reinterpret_cast<const bf16x8*>(&sW1T[n * 32 + ((lg * 8) ^ ((n & 3) << 3))]);
            float bias = sB1[n];
            f32x4 c = { bias, bias, bias, bias };
            c = __builtin_amdgcn_mfma_f32_16x16x32_bf16(a, b, c, 0, 0, 0);
            #pragma unroll
            for (int r = 0; r < 4; ++r) {
                int e = w * 16 + lg * 4 + r;              // C row = (lane>>4)*4 + reg  [m89-verified]
                sA[e * 128 + (n ^ ((e & 7) << 3))] = f32_bf16(fmaxf(c[r], 0.0f));
            }
        }
    }
    __syncthreads();

    // layer 2 GEMM [64x128]@[128x512] in 4 N-chunks of 128, fused msg contraction
    float msgv[4][2] = {{0.f,0.f},{0.f,0.f},{0.f,0.f},{0.f,0.f}};

    for (int chunk = 0; chunk < 4; ++chunk) {
        // stage W2T rows chunk*128..+128 into sB, swizzle k ^= (n&7)<<3
        #pragma unroll
        for (int p = 0; p < 8; ++p) {
            int r = p * 16 + (tid >> 4);
            int g = tid & 15;
            uint4 v = *reinterpret_cast<const uint4*>(&w2t[(chunk * 128 + r) * 128 + g * 8]);
            *reinterpret_cast<uint4*>(&sB[r * 128 + ((g * 8) ^ ((r & 7) << 3))]) = v;
        }
        __syncthreads();

        f32x4 acc[8];
        #pragma unroll
        for (int f = 0; f < 8; ++f) { f32x4 z = {0.f,0.f,0.f,0.f}; acc[f] = z; }

        #pragma unroll
        for (int kb = 0; kb < 4; ++kb) {
            int row = w * 16 + l15;
            int ka  = kb * 32 + lg * 8;
            bf16x8 a = *reinterpret_cast<const bf16x8*>(&sA[row * 128 + (ka ^ ((row & 7) << 3))]);
            #pragma unroll
            for (int f = 0; f < 8; ++f) {
                int n = f * 16 + l15;
                bf16x8 b = *reinterpret_cast<const bf16x8*>(&sB[n * 128 + (ka ^ ((n & 7) << 3))]);
                acc[f] = __builtin_amdgcn_mfma_f32_16x16x32_bf16(a, b, acc[f], 0, 0, 0);
            }
        }

        // epilogue: msg[e][h] += x[e][i] * ew[e][i*32+h];  col = chunk*128 + f*16 + l15
        #pragma unroll
        for (int f = 0; f < 8; ++f) {
            int i = chunk * 4 + (f >> 1);
            int p = f & 1;
            #pragma unroll
            for (int r = 0; r < 4; ++r) {
                int e = w * 16 + lg * 4 + r;
                msgv[r][p] += sX[e * 16 + i] * acc[f][r];
            }
        }
        __syncthreads();
    }

    // scatter: agg[dst][h] += msg + x·b2
    #pragma unroll
    for (int r = 0; r < 4; ++r) {
        int e = w * 16 + lg * 4 + r;
        int d = sDst[e];
        #pragma unroll
        for (int p = 0; p < 2; ++p) {
            int hh = p * 16 + l15;
            float xb2 = 0.f;
            #pragma unroll
            for (int i = 0; i < 16; ++i) xb2 += sX[e * 16 + i] * sB2[i * 32 + hh];
            atomicAdd(&agg[d * 32 + hh], msgv[r][p] + xb2);
        }
    }
}

// ---------------- h = relu(agg/max(deg,1) + conv_b) ----------------
__global__ void finalize_h(const float* __restrict__ agg, const float* __restrict__ deg,
                           const float* __restrict__ conv_b, float* __restrict__ h) {
    int tid = blockIdx.x * 256 + threadIdx.x;
    if (tid >= N_NODES * HIDDEN) return;
    int v = tid >> 5, f = tid & 31;
    float d = fmaxf(deg[v], 1.0f);
    h[tid] = fmaxf(agg[tid] / d + conv_b[f], 0.0f);
}

// ---------------- classifier on 100K selected edges ----------------
__global__ __launch_bounds__(256) void classifier(
    const float* __restrict__ h, const float* __restrict__ ef,
    const int* __restrict__ src, const int* __restrict__ dst, const int* __restrict__ eidx,
    const float* __restrict__ w1, const float* __restrict__ b1,
    const float* __restrict__ w2, const float* __restrict__ b2, float* __restrict__ out)
{
    __shared__ float sIn[8][80];
    __shared__ float sW1[80 * 32];
    __shared__ float sHid[8][32];
    __shared__ int   sE[8 * 3];
    int tid = threadIdx.x;
    int eb  = blockIdx.x * 8;

    for (int i = tid; i < 80 * 32; i += 256) sW1[i] = w1[i];
    if (tid < 8) {
        int ei = eidx[eb + tid];
        sE[tid * 3 + 0] = ei;
        sE[tid * 3 + 1] = src[ei];
        sE[tid * 3 + 2] = dst[ei];
    }
    __syncthreads();
    for (int idx = tid; idx < 8 * 80; idx += 256) {
        int e = idx / 80, c = idx % 80;
        float v;
        if (c < 32)      v = h[sE[e * 3 + 1] * 32 + c];
        else if (c < 64) v = h[sE[e * 3 + 2] * 32 + (c - 32)];
        else             v = ef[sE[e * 3 + 0] * 16 + (c - 64)];
        sIn[e][c] = v;
    }
    __syncthreads();
    {
        int e = tid >> 5, j = tid & 31;
        float acc = b1[j];
        #pragma unroll
        for (int k = 0; k < 80; ++k) acc += sIn[e][k] * sW1[k * 32 + j];
        sHid[e][j] = fmaxf(acc, 0.0f);
    }
    __syncthreads();
    if (tid < 16) {
        int e = tid >> 1, o = tid & 1;
        float acc = b2[o];
        #pragma unroll
        for (int j = 0; j < 32; ++j) acc += sHid[e][j] * w2[j * 2 + o];
        out[(eb + e) * 2 + o] = acc;
    }
}

extern "C" void kernel_launch(void* const* d_in, const int* in_sizes, int n_in,
                              void* d_out, int out_size, void* d_ws, size_t ws_size,
                              hipStream_t stream) {
    const float* nf     = (const float*)d_in[0];
    const float* ef     = (const float*)d_in[1];
    const int*   src    = (const int*)d_in[2];
    const int*   dst    = (const int*)d_in[3];
    const int*   eidx   = (const int*)d_in[4];
    const float* en_w1  = (const float*)d_in[5];
    const float* en_b1  = (const float*)d_in[6];
    const float* en_w2  = (const float*)d_in[7];
    const float* en_b2  = (const float*)d_in[8];
    const float* conv_b = (const float*)d_in[9];
    const float* cls_w1 = (const float*)d_in[10];
    const float* cls_b1 = (const float*)d_in[11];
    const float* cls_w2 = (const float*)d_in[12];
    const float* cls_b2 = (const float*)d_in[13];
    float* out = (float*)d_out;

    char* ws = (char*)d_ws;
    unsigned short* w2t = (unsigned short*)(ws);               // 131072 B
    unsigned short* w1t = (unsigned short*)(ws + 131072);      // 8192 B
    float* agg = (float*)(ws + 139264);                        // 6,400,000 B
    float* deg = (float*)(ws + 139264 + 6400000);              // 200,000 B
    float* h   = (float*)(ws + 139264 + 6600000);              // 6,400,000 B

    // zero agg+deg (contiguous 1,650,000 floats) every call — ws is not re-poisoned between replays
    zero_f32<<<(1650000 + 255) / 256, 256, 0, stream>>>(agg, 1650000);
    prep_weights<<<(NOUT * K1 + 4096) / 256, 256, 0, stream>>>(en_w2, en_w1, w2t, w1t);
    fused_msg<<<N_EDGES / TILE_E, 256, 0, stream>>>(nf, ef, src, dst, w1t, en_b1, w2t, en_b2, agg, deg);
    finalize_h<<<(N_NODES * HIDDEN + 255) / 256, 256, 0, stream>>>(agg, deg, conv_b, h);
    classifier<<<N_CLS / 8, 256, 0, stream>>>(h, ef, src, dst, eidx, cls_w1, cls_b1, cls_w2, cls_b2, out);
}